// Round 3
// baseline (304.652 us; speedup 1.0000x reference)
//
#include <hip/hip_runtime.h>

// Problem constants (match reference)
#define BATCH   8
#define LEN     2048
#define DMODEL  512
#define T_MAX   200.0f

// clang-native 4-float vector for __builtin_nontemporal_store.
typedef float floatx4 __attribute__((ext_vector_type(4)));

// Persistent-ish fused kernel (2560 blocks total):
//  - blocks [0, EMB_BLOCKS): embedding. Each block owns 32 consecutive rows;
//    256 threads = 2 rows per pass (128 thr/row, float4/thread), 16 passes.
//    The 10000^(-2d/D) factors are computed ONCE per thread, reused 16x.
//  - blocks [EMB_BLOCKS, EMB_BLOCKS+SC_BLOCKS): scores+t_diff. Each block owns
//    8 consecutive rows (same batch: 2048 % 8 == 0). The tj[8] column values
//    and the softplus/sigmoid params are loaded/computed ONCE and reused for
//    all 8 rows — 8x less L2 read traffic and 8x fewer block launches than
//    the 1-row-per-block version.
// All stores non-temporal (pure streaming output, never re-read).
// Per-element math is bit-identical to the verified 295us kernel.

#define EMB_BLOCKS 512                   // 16384 rows / 32 rows per block
#define SC_BLOCKS  2048                  // 16384 rows / 8 rows per block

__global__ __launch_bounds__(256) void fused_encoder_kernel(
    const float* __restrict__ t,        // [B*L]
    const float* __restrict__ ls_p,     // [1]
    const float* __restrict__ gate_p,   // [2]
    float* __restrict__ scores,         // [B,L,L]
    float* __restrict__ emb,            // [B,L,DMODEL]
    float* __restrict__ tdiff)          // [B,L,L]
{
    const int bid = blockIdx.x;
    const int tid = threadIdx.x;

    if (bid < EMB_BLOCKS) {
        // ---------------- embedding path ----------------
        const int d0   = (tid & 127) * 4;            // dim offset, 128 thr/row
        const int half = tid >> 7;                   // 0 or 1
        const int rbase = bid * 32;
        const float c = -9.210340371976184f * (2.0f / (float)DMODEL); // -ln(1e4)*2/D

        // 10000^(-2*dim/D) for the 4 dims this thread owns — row-invariant
        const float ip0 = __expf(c * (float)(d0 + 0));
        const float ip1 = __expf(c * (float)(d0 + 1));
        const float ip2 = __expf(c * (float)(d0 + 2));
        const float ip3 = __expf(c * (float)(d0 + 3));

#pragma unroll
        for (int p = 0; p < 16; ++p) {
            const int row = rbase + p * 2 + half;
            const float tv = t[row];
            floatx4 e;
            e.x = __sinf(tv * ip0);   // even dim -> sin
            e.y = __cosf(tv * ip1);   // odd dim  -> cos
            e.z = __sinf(tv * ip2);
            e.w = __cosf(tv * ip3);
            __builtin_nontemporal_store(
                e, (floatx4*)(emb + (size_t)row * DMODEL + d0));
        }
        return;
    }

    // ---------------- scores + t_diff path ----------------
    const int sb   = bid - EMB_BLOCKS;
    const int row0 = sb * 8;             // first of 8 consecutive rows
    const int b    = row0 >> 11;         // batch (8 rows never cross a batch)
    const int i0   = row0 & (LEN - 1);
    const int c0   = tid * 4;            // cols [0,1024)
    const int c1   = 1024 + c0;          // cols [1024,2048)

    // learned params (wave-uniform, computed once for all 8 rows)
    const float ls      = log1pf(__expf(ls_p[0]));            // softplus
    const float inv_ls2 = 1.0f / (ls * ls);
    const float l = 1.0f / (1.0f + __expf(-gate_p[0]));       // sigmoid
    const float s = 1.0f / (1.0f + __expf(-gate_p[1]));
    const float inv_s2 = 2.0f / s;                            // for 2*u
    const float invT   = 1.0f / T_MAX;

    // column times (row-invariant within the batch) — loaded once
    const float* trow = t + b * LEN;
    float4 ta = *(const float4*)(trow + c0);
    float4 tb = *(const float4*)(trow + c1);
    float tj[8]  = {ta.x, ta.y, ta.z, ta.w, tb.x, tb.y, tb.z, tb.w};
    int   col[8] = {c0, c0 + 1, c0 + 2, c0 + 3, c1, c1 + 1, c1 + 2, c1 + 3};

    // the 8 row times — two float4 loads
    float4 tia = *(const float4*)(t + row0);
    float4 tib = *(const float4*)(t + row0 + 4);
    float ti[8] = {tia.x, tia.y, tia.z, tia.w, tib.x, tib.y, tib.z, tib.w};

#pragma unroll
    for (int r = 0; r < 8; ++r) {
        const int i = i0 + r;
        const float tir = ti[r];
        float sc[8], td[8];
#pragma unroll
        for (int k = 0; k < 8; ++k) {
            float d  = tir - tj[k];
            float ad = fabsf(d);
            float kern = __expf(-ad * ad * inv_ls2);
            float u2 = (ad * invT - l) * inv_s2;              // 2*(d/T-l)/s
            // 1 + tanh(u) == 2 * sigmoid(2u)
            float gate = __fdividef(2.0f, 1.0f + __expf(-u2));
            sc[k] = (col[k] <= i) ? kern * gate : 0.0f;
            td[k] = d;
        }
        const size_t base = (size_t)(row0 + r) * LEN;
        floatx4 s0 = {sc[0], sc[1], sc[2], sc[3]};
        floatx4 s1 = {sc[4], sc[5], sc[6], sc[7]};
        floatx4 d0v = {td[0], td[1], td[2], td[3]};
        floatx4 d1v = {td[4], td[5], td[6], td[7]};
        __builtin_nontemporal_store(s0, (floatx4*)(scores + base + c0));
        __builtin_nontemporal_store(s1, (floatx4*)(scores + base + c1));
        __builtin_nontemporal_store(d0v, (floatx4*)(tdiff + base + c0));
        __builtin_nontemporal_store(d1v, (floatx4*)(tdiff + base + c1));
    }
}

extern "C" void kernel_launch(void* const* d_in, const int* in_sizes, int n_in,
                              void* d_out, int out_size, void* d_ws, size_t ws_size,
                              hipStream_t stream) {
    // inputs: [0]=event_type (int, unused), [1]=event_time (f32, B*L),
    //         [2]=length_scale_param (f32,1), [3]=gate_params (f32,2)
    const float* t      = (const float*)d_in[1];
    const float* ls_p   = (const float*)d_in[2];
    const float* gate_p = (const float*)d_in[3];

    float* out = (float*)d_out;
    const size_t n_scores = (size_t)BATCH * LEN * LEN;    // 33554432
    const size_t n_emb    = (size_t)BATCH * LEN * DMODEL; // 8388608
    float* scores = out;
    float* emb    = out + n_scores;
    float* tdiff  = out + n_scores + n_emb;

    fused_encoder_kernel<<<EMB_BLOCKS + SC_BLOCKS, 256, 0, stream>>>(
        t, ls_p, gate_p, scores, emb, tdiff);
}